// Round 12
// baseline (231.868 us; speedup 1.0000x reference)
//
#include <hip/hip_runtime.h>
#include <hip/hip_bf16.h>

#define N 8192
#define IN_F 256
#define HEADS 4
#define HF 64
#define OUT_F 256

typedef __attribute__((ext_vector_type(8))) short short8;
typedef __attribute__((ext_vector_type(4))) float f32x4;

__device__ __forceinline__ float lrelu(float x) {
    return fmaxf(x, 0.0f) * 0.8f + x * 0.2f;
}
__device__ __forceinline__ short f2bf(float f) {
    union { __hip_bfloat16 h; short s; } u;
    u.h = __float2bfloat16(f);
    return u.s;
}
__device__ __forceinline__ float bf2f(unsigned short b) {
    union { unsigned u; float f; } v; v.u = ((unsigned)b) << 16;
    return v.f;
}
__device__ __forceinline__ unsigned pack_bf16(float p0, float p1) {
    union { __hip_bfloat162 b; unsigned u; } cv;
    cv.b = __float22bfloat162_rn(make_float2(p0, p1));
    return cv.u;
}

// K0: build BbT[c][k] bf16, c<256 -> W heads, c>=256 -> Wr
__global__ __launch_bounds__(256) void k_wcvt(
    const float* __restrict__ w, const float* __restrict__ wr,
    unsigned short* __restrict__ BbT)
{
    int c = blockIdx.x;
    int k = threadIdx.x;
    float v;
    if (c < 256) {
        int head = c >> 6, f = c & 63;
        v = w[((size_t)head * IN_F + k) * HF + f];
    } else {
        v = wr[(size_t)k * OUT_F + (c - 256)];
    }
    BbT[(size_t)c * IN_F + k] = (unsigned short)f2bf(v);
}

// K1: MERGED gemm + pack. Blocks 0..511: fused GEMM [8192x256]@[256x512]
// -> hT | out residual. Blocks 512..8703: graph bit-pack (HBM-bound; the
// gemm blocks hide under its HBM stream).
__global__ __launch_bounds__(256) void k_gemm_pack(
    const float* __restrict__ x, const unsigned short* __restrict__ BbT,
    const float* __restrict__ bias,
    unsigned short* __restrict__ hT, float* __restrict__ out,
    const int* __restrict__ graph, unsigned int* __restrict__ bits)
{
    __shared__ unsigned short Asw[64 * 64];
    __shared__ unsigned short Bsw[128 * 64];
    int b = blockIdx.x;
    int t = threadIdx.x;

    if (b >= 512) {
        int p = b - 512;
        int jw = p & 255;
        int i = (p >> 8) * 256 + t;
        const int* gp = graph + (size_t)(jw * 32) * N + i;
        unsigned int word = 0;
        #pragma unroll
        for (int k = 0; k < 32; ++k)
            word |= (gp[(size_t)k * N] > 0 ? 1u : 0u) << k;
        bits[(size_t)jw * N + i] = word;
        return;
    }

    int m0 = (b & 127) * 64;
    int bn = b >> 7;
    int w_ = t >> 6, l = t & 63;
    int wr_ = w_ >> 1, wc_ = w_ & 1;
    int ar = l & 15, g = l >> 4;

    f32x4 acc[2][4];
    #pragma unroll
    for (int m = 0; m < 2; ++m)
        #pragma unroll
        for (int n = 0; n < 4; ++n) acc[m][n] = (f32x4){0.f, 0.f, 0.f, 0.f};

    int srow = t >> 2, skq = (t & 3) * 16;
    int sc = t >> 1, sh = (t & 1) * 32;

    for (int kt = 0; kt < 4; ++kt) {
        const float* xs = x + (size_t)(m0 + srow) * IN_F + kt * 64 + skq;
        float4 xa = ((const float4*)xs)[0];
        float4 xb = ((const float4*)xs)[1];
        float4 xc = ((const float4*)xs)[2];
        float4 xd = ((const float4*)xs)[3];
        unsigned ae[8];
        ae[0] = pack_bf16(xa.x, xa.y); ae[1] = pack_bf16(xa.z, xa.w);
        ae[2] = pack_bf16(xb.x, xb.y); ae[3] = pack_bf16(xb.z, xb.w);
        ae[4] = pack_bf16(xc.x, xc.y); ae[5] = pack_bf16(xc.z, xc.w);
        ae[6] = pack_bf16(xd.x, xd.y); ae[7] = pack_bf16(xd.z, xd.w);
        int kb0 = (skq >> 3) ^ (srow & 7);
        int kb1 = ((skq >> 3) + 1) ^ (srow & 7);
        *(uint4*)&Asw[srow * 64 + kb0 * 8] = *(uint4*)&ae[0];
        *(uint4*)&Asw[srow * 64 + kb1 * 8] = *(uint4*)&ae[4];
        const unsigned short* bs = BbT + (size_t)(bn * 128 + sc) * IN_F + kt * 64 + sh;
        uint4 b0 = ((const uint4*)bs)[0];
        uint4 b1 = ((const uint4*)bs)[1];
        uint4 b2 = ((const uint4*)bs)[2];
        uint4 b3 = ((const uint4*)bs)[3];
        int hb = sh >> 3;
        *(uint4*)&Bsw[sc * 64 + ((hb + 0) ^ (sc & 7)) * 8] = b0;
        *(uint4*)&Bsw[sc * 64 + ((hb + 1) ^ (sc & 7)) * 8] = b1;
        *(uint4*)&Bsw[sc * 64 + ((hb + 2) ^ (sc & 7)) * 8] = b2;
        *(uint4*)&Bsw[sc * 64 + ((hb + 3) ^ (sc & 7)) * 8] = b3;
        __syncthreads();
        #pragma unroll
        for (int ks = 0; ks < 2; ++ks) {
            short8 af[2], bf[4];
            #pragma unroll
            for (int m = 0; m < 2; ++m) {
                int row = wr_ * 32 + m * 16 + ar;
                int kb = (ks * 4 + g) ^ (row & 7);
                af[m] = *(const short8*)&Asw[row * 64 + kb * 8];
            }
            #pragma unroll
            for (int n = 0; n < 4; ++n) {
                int c = wc_ * 64 + n * 16 + ar;
                int kb = (ks * 4 + g) ^ (c & 7);
                bf[n] = *(const short8*)&Bsw[c * 64 + kb * 8];
            }
            #pragma unroll
            for (int m = 0; m < 2; ++m)
                #pragma unroll
                for (int n = 0; n < 4; ++n)
                    acc[m][n] = __builtin_amdgcn_mfma_f32_16x16x32_bf16(af[m], bf[n], acc[m][n], 0, 0, 0);
        }
        __syncthreads();
    }
    #pragma unroll
    for (int m = 0; m < 2; ++m) {
        #pragma unroll
        for (int n = 0; n < 4; ++n) {
            int cg = bn * 128 + wc_ * 64 + n * 16 + ar;
            int mg0 = m0 + wr_ * 32 + m * 16 + g * 4;
            if (cg < 256) {
                int head = cg >> 6, f = cg & 63;
                unsigned pk[2];
                pk[0] = pack_bf16(acc[m][n][0], acc[m][n][1]);
                pk[1] = pack_bf16(acc[m][n][2], acc[m][n][3]);
                *(uint2*)(hT + (size_t)(head * HF + f) * N + mg0) = *(uint2*)pk;
            } else {
                float bb = bias[cg - 256];
                #pragma unroll
                for (int r = 0; r < 4; ++r)
                    out[(size_t)(mg0 + r) * OUT_F + (cg - 256)] = acc[m][n][r] + bb;
            }
        }
    }
}

// K2: coe_i/coe_j from hT (column-major dot, coalesced)
__global__ __launch_bounds__(256) void k_coe(
    const unsigned short* __restrict__ hT, const float* __restrict__ wi,
    const float* __restrict__ wj, float* __restrict__ coe_i, float* __restrict__ coe_j)
{
    int head = blockIdx.y;
    int n = blockIdx.x * 256 + threadIdx.x;
    const unsigned short* hp = hT + (size_t)head * HF * N + n;
    float si = 0.f, sj = 0.f;
    #pragma unroll 8
    for (int f = 0; f < HF; ++f) {
        float hv = bf2f(hp[(size_t)f * N]);
        si = fmaf(hv, wi[head * HF + f], si);
        sj = fmaf(hv, wj[head * HF + f], sj);
    }
    coe_i[head * N + n] = si;
    coe_j[head * N + n] = sj;
}

// K3: per head: maxB + column factor arrays F=exp(b), H=exp(0.2b)
__global__ __launch_bounds__(256) void k_cols(
    const float* __restrict__ coe_j, float* __restrict__ maxB,
    float* __restrict__ F, float* __restrict__ H)
{
    __shared__ float red[256];
    int head = blockIdx.x;
    int t = threadIdx.x;
    float m = -1e30f;
    for (int n = t; n < N; n += 256) {
        float b = coe_j[head * N + n];
        F[head * N + n] = __expf(b);
        H[head * N + n] = __expf(0.2f * b);
        m = fmaxf(m, b);
    }
    red[t] = m;
    __syncthreads();
    for (int s = 128; s > 0; s >>= 1) {
        if (t < s) red[t] = fmaxf(red[t], red[t + s]);
        __syncthreads();
    }
    if (t == 0) maxB[head] = red[0];
}

// P for 8 columns: p = max(Ei*F, Gi*H) (= exp(lrelu(a+b)-M)); mask via sbfe.
__device__ __forceinline__ short8 makeP(
    const float4& fa, const float4& fb4, const float4& ha, const float4& hb4,
    unsigned int mk, float Ei, float Gi)
{
    float fv[8] = {fa.x, fa.y, fa.z, fa.w, fb4.x, fb4.y, fb4.z, fb4.w};
    float hv[8] = {ha.x, ha.y, ha.z, ha.w, hb4.x, hb4.y, hb4.z, hb4.w};
    union { short8 s8; unsigned u[4]; } A;
    #pragma unroll
    for (int jp = 0; jp < 4; ++jp) {
        float p0 = fmaxf(Ei * fv[2 * jp],     Gi * hv[2 * jp]);
        float p1 = fmaxf(Ei * fv[2 * jp + 1], Gi * hv[2 * jp + 1]);
        int s0 = __builtin_amdgcn_sbfe((int)mk, 2 * jp, 1);
        int s1 = __builtin_amdgcn_sbfe((int)mk, 2 * jp + 1, 1);
        p0 = __int_as_float(__float_as_int(p0) & s0);
        p1 = __int_as_float(__float_as_int(p1) & s1);
        A.u[jp] = pack_bf16(p0, p1);
    }
    return A.s8;
}

#define MFMA16 __builtin_amdgcn_mfma_f32_16x16x32_bf16

// One 64-j phase: consume prefetched B-frags (C0..C7) + masks (cm*), prefetch
// next iteration's into (P0..P7, pm*). F/H loaded here (L1 broadcasts).
#define PHASE(C0,C1,C2,C3,C4,C5,C6,C7, P0,P1,P2,P3,P4,P5,P6,P7, \
              cm00,cm01,cm10,cm11, pm00,pm01,pm10,pm11, JT, JTN) do { \
    float4 fa0 = *(const float4*)(Fp + (JT)); \
    float4 fb0 = *(const float4*)(Fp + (JT) + 4); \
    float4 ha0 = *(const float4*)(Hp + (JT)); \
    float4 hb0 = *(const float4*)(Hp + (JT) + 4); \
    float4 fa1 = *(const float4*)(Fp + (JT) + 32); \
    float4 fb1 = *(const float4*)(Fp + (JT) + 36); \
    float4 ha1 = *(const float4*)(Hp + (JT) + 32); \
    float4 hb1 = *(const float4*)(Hp + (JT) + 36); \
    size_t jwn_ = (size_t)((JTN) >> 5); \
    pm00 = bp0[jwn_ * N] >> g8; \
    pm01 = bp0[(jwn_ + 1) * N] >> g8; \
    pm10 = bp1[jwn_ * N] >> g8; \
    pm11 = bp1[(jwn_ + 1) * N] >> g8; \
    const unsigned short* hs_ = hB + (JTN); \
    P0 = *(const short8*)(hs_); \
    P1 = *(const short8*)(hs_ + 16 * (size_t)N); \
    P2 = *(const short8*)(hs_ + 32 * (size_t)N); \
    P3 = *(const short8*)(hs_ + 48 * (size_t)N); \
    P4 = *(const short8*)(hs_ + 32); \
    P5 = *(const short8*)(hs_ + 32 + 16 * (size_t)N); \
    P6 = *(const short8*)(hs_ + 32 + 32 * (size_t)N); \
    P7 = *(const short8*)(hs_ + 32 + 48 * (size_t)N); \
    short8 af00 = makeP(fa0, fb0, ha0, hb0, cm00, Ei0, Gi0); \
    short8 af10 = makeP(fa0, fb0, ha0, hb0, cm10, Ei1, Gi1); \
    short8 af01 = makeP(fa1, fb1, ha1, hb1, cm01, Ei0, Gi0); \
    short8 af11 = makeP(fa1, fb1, ha1, hb1, cm11, Ei1, Gi1); \
    __builtin_amdgcn_s_setprio(1); \
    acc0[0] = MFMA16(af00, C0, acc0[0], 0, 0, 0); \
    acc1[0] = MFMA16(af10, C0, acc1[0], 0, 0, 0); \
    acc0[1] = MFMA16(af00, C1, acc0[1], 0, 0, 0); \
    acc1[1] = MFMA16(af10, C1, acc1[1], 0, 0, 0); \
    acc0[2] = MFMA16(af00, C2, acc0[2], 0, 0, 0); \
    acc1[2] = MFMA16(af10, C2, acc1[2], 0, 0, 0); \
    acc0[3] = MFMA16(af00, C3, acc0[3], 0, 0, 0); \
    acc1[3] = MFMA16(af10, C3, acc1[3], 0, 0, 0); \
    accd0 = MFMA16(af00, ones, accd0, 0, 0, 0); \
    accd1 = MFMA16(af10, ones, accd1, 0, 0, 0); \
    acc0[0] = MFMA16(af01, C4, acc0[0], 0, 0, 0); \
    acc1[0] = MFMA16(af11, C4, acc1[0], 0, 0, 0); \
    acc0[1] = MFMA16(af01, C5, acc0[1], 0, 0, 0); \
    acc1[1] = MFMA16(af11, C5, acc1[1], 0, 0, 0); \
    acc0[2] = MFMA16(af01, C6, acc0[2], 0, 0, 0); \
    acc1[2] = MFMA16(af11, C6, acc1[2], 0, 0, 0); \
    acc0[3] = MFMA16(af01, C7, acc0[3], 0, 0, 0); \
    acc1[3] = MFMA16(af11, C7, acc1[3], 0, 0, 0); \
    accd0 = MFMA16(af01, ones, accd0, 0, 0, 0); \
    accd1 = MFMA16(af11, ones, accd1, 0, 0, 0); \
    __builtin_amdgcn_s_setprio(0); \
} while (0)

// K5: flash aggregate, BARRIER-FREE main loop, explicit ping-pong software
// pipeline: B-fragments + mask words for iteration s+1 prefetched into NAMED
// registers while iteration s's MFMA block (consuming only prefetched regs)
// executes. 8 waves = (rg:2 row-halves) x (jq:4 j-quarters), fully independent.
__global__ __launch_bounds__(512) void k_att(
    const unsigned short* __restrict__ hT, const float* __restrict__ coe_i,
    const float* __restrict__ maxB, const float* __restrict__ F,
    const float* __restrict__ H, const unsigned int* __restrict__ bits,
    float* __restrict__ out)
{
    __shared__ float mbuf[3 * 128 * 41];

    int t = threadIdx.x;
    // XCD-aware swizzle (bijective): head = (bid>>1)&3 -> head h on XCDs {2h,2h+1}.
    int bid = blockIdx.x + gridDim.x * blockIdx.y;
    int head = (bid >> 1) & 3;
    int i_idx = ((bid >> 3) << 1) | (bid & 1);
    int i0 = i_idx * 64;

    int w = t >> 6, l = t & 63;
    int rg = w >> 2, jq = w & 3;
    int ar = l & 15, g = l >> 4, g8 = g * 8;

    int irow0 = i0 + rg * 32 + ar;
    int irow1 = irow0 + 16;
    float mB = maxB[head];
    float a0 = coe_i[head * N + irow0];
    float a1 = coe_i[head * N + irow1];
    float M0 = lrelu(a0 + mB);
    float M1 = lrelu(a1 + mB);
    float Ei0 = __expf(a0 - M0), Gi0 = __expf(0.2f * a0 - M0);
    float Ei1 = __expf(a1 - M1), Gi1 = __expf(0.2f * a1 - M1);

    f32x4 acc0[4], acc1[4];
    #pragma unroll
    for (int fb = 0; fb < 4; ++fb) {
        acc0[fb] = (f32x4){0.f, 0.f, 0.f, 0.f};
        acc1[fb] = (f32x4){0.f, 0.f, 0.f, 0.f};
    }
    f32x4 accd0 = (f32x4){0.f, 0.f, 0.f, 0.f};
    f32x4 accd1 = (f32x4){0.f, 0.f, 0.f, 0.f};

    short8 ones;
    #pragma unroll
    for (int k = 0; k < 8; ++k) ones[k] = (short)0x3F80;

    const float* Fp = F + head * N + g8;
    const float* Hp = H + head * N + g8;
    const unsigned int* bp0 = bits + irow0;
    const unsigned int* bp1 = bits + irow1;
    const unsigned short* hB = hT + ((size_t)(head * HF + ar) * N) + g8;

    int j0 = jq * (N / 4);

    // prolog: prefetch iteration 0's B-frags + masks
    short8 BA0, BA1, BA2, BA3, BA4, BA5, BA6, BA7;
    short8 BB0, BB1, BB2, BB3, BB4, BB5, BB6, BB7;
    unsigned mA00, mA01, mA10, mA11, mB00, mB01, mB10, mB11;
    {
        const unsigned short* hs = hB + j0;
        BA0 = *(const short8*)(hs);
        BA1 = *(const short8*)(hs + 16 * (size_t)N);
        BA2 = *(const short8*)(hs + 32 * (size_t)N);
        BA3 = *(const short8*)(hs + 48 * (size_t)N);
        BA4 = *(const short8*)(hs + 32);
        BA5 = *(const short8*)(hs + 32 + 16 * (size_t)N);
        BA6 = *(const short8*)(hs + 32 + 32 * (size_t)N);
        BA7 = *(const short8*)(hs + 32 + 48 * (size_t)N);
        size_t jw0 = (size_t)(j0 >> 5);
        mA00 = bp0[jw0 * N] >> g8;
        mA01 = bp0[(jw0 + 1) * N] >> g8;
        mA10 = bp1[jw0 * N] >> g8;
        mA11 = bp1[(jw0 + 1) * N] >> g8;
    }

    int jt = j0;
    #pragma unroll 1
    for (int s = 0; s < 16; ++s) {
        int jt1 = jt + 64;
        int jt2 = (s < 15) ? jt + 128 : j0;   // final prefetch wraps (discarded)
        PHASE(BA0, BA1, BA2, BA3, BA4, BA5, BA6, BA7,
              BB0, BB1, BB2, BB3, BB4, BB5, BB6, BB7,
              mA00, mA01, mA10, mA11, mB00, mB01, mB10, mB11, jt, jt1);
        PHASE(BB0, BB1, BB2, BB3, BB4, BB5, BB6, BB7,
              BA0, BA1, BA2, BA3, BA4, BA5, BA6, BA7,
              mB00, mB01, mB10, mB11, mA00, mA01, mA10, mA11, jt1, jt2);
        jt += 128;
    }

    // 4-way jq merge through LDS (only barriers in the kernel)
    int slot = rg * 64 + l;
    if (jq > 0) {
        float* dst = mbuf + (size_t)(jq - 1) * 5248 + slot * 41;
        #pragma unroll
        for (int fb = 0; fb < 4; ++fb)
            #pragma unroll
            for (int r = 0; r < 4; ++r) {
                dst[fb * 4 + r] = acc0[fb][r];
                dst[16 + fb * 4 + r] = acc1[fb][r];
            }
        #pragma unroll
        for (int r = 0; r < 4; ++r) {
            dst[32 + r] = accd0[r];
            dst[36 + r] = accd1[r];
        }
    }
    __syncthreads();
    if (jq == 0) {
        #pragma unroll
        for (int q = 0; q < 3; ++q) {
            const float* src = mbuf + (size_t)q * 5248 + slot * 41;
            #pragma unroll
            for (int fb = 0; fb < 4; ++fb)
                #pragma unroll
                for (int r = 0; r < 4; ++r) {
                    acc0[fb][r] += src[fb * 4 + r];
                    acc1[fb][r] += src[16 + fb * 4 + r];
                }
            #pragma unroll
            for (int r = 0; r < 4; ++r) {
                accd0[r] += src[32 + r];
                accd1[r] += src[36 + r];
            }
        }
        #pragma unroll
        for (int r = 0; r < 4; ++r) {
            float inv0 = 1.0f / accd0[r];
            float inv1 = 1.0f / accd1[r];
            int orow0 = i0 + rg * 32 + g * 4 + r;
            float* op0 = out + (size_t)orow0 * OUT_F + head * HF + ar;
            float* op1 = op0 + 16 * OUT_F;
            #pragma unroll
            for (int fb = 0; fb < 4; ++fb) {
                op0[fb * 16] += acc0[fb][r] * inv0;
                op1[fb * 16] += acc1[fb][r] * inv1;
            }
        }
    }
}

extern "C" void kernel_launch(void* const* d_in, const int* in_sizes, int n_in,
                              void* d_out, int out_size, void* d_ws, size_t ws_size,
                              hipStream_t stream) {
    const float* x     = (const float*)d_in[0];
    const int*   graph = (const int*)d_in[1];
    const float* w     = (const float*)d_in[2];
    const float* wi    = (const float*)d_in[3];
    const float* wj    = (const float*)d_in[4];
    const float* wr    = (const float*)d_in[5];
    const float* bias  = (const float*)d_in[6];
    float* out = (float*)d_out;

    char* ws = (char*)d_ws;
    unsigned short* hT  = (unsigned short*)(ws);                    // 4,194,304
    float* coe_i = (float*)(ws + 4194304);                          // 131072
    float* coe_j = (float*)(ws + 4325376);                          // 131072
    float* maxB  = (float*)(ws + 4456448);                          // 1024
    float* F     = (float*)(ws + 4457472);                          // 131072
    float* H     = (float*)(ws + 4588544);                          // 131072
    unsigned short* BbT = (unsigned short*)(ws + 4719616);          // 262144
    unsigned int* bits  = (unsigned int*)(ws + 4981760);            // 8,388,608

    k_wcvt<<<dim3(512), 256, 0, stream>>>(w, wr, BbT);
    k_gemm_pack<<<dim3(512 + 8192), 256, 0, stream>>>(x, BbT, bias, hT, out, graph, bits);
    k_coe<<<dim3(32, 4), 256, 0, stream>>>(hT, wi, wj, coe_i, coe_j);
    k_cols<<<dim3(4), 256, 0, stream>>>(coe_j, maxB, F, H);
    k_att<<<dim3(N / 64, HEADS), 512, 0, stream>>>(hT, coe_i, maxB, F, H, bits, out);
}

// Round 13
// 164.016 us; speedup vs baseline: 1.4137x; 1.4137x over previous
//
#include <hip/hip_runtime.h>
#include <hip/hip_bf16.h>

#define N 8192
#define IN_F 256
#define HEADS 4
#define HF 64
#define OUT_F 256

typedef __attribute__((ext_vector_type(8))) short short8;
typedef __attribute__((ext_vector_type(4))) float f32x4;

__device__ __forceinline__ float lrelu(float x) {
    return fmaxf(x, 0.0f) * 0.8f + x * 0.2f;
}
__device__ __forceinline__ short f2bf(float f) {
    union { __hip_bfloat16 h; short s; } u;
    u.h = __float2bfloat16(f);
    return u.s;
}
__device__ __forceinline__ float bf2f(unsigned short b) {
    union { unsigned u; float f; } v; v.u = ((unsigned)b) << 16;
    return v.f;
}
__device__ __forceinline__ unsigned pack_bf16(float p0, float p1) {
    union { __hip_bfloat162 b; unsigned u; } cv;
    cv.b = __float22bfloat162_rn(make_float2(p0, p1));
    return cv.u;
}

// direct global->LDS DMA, 16B per lane; LDS dest is wave-uniform base + lane*16
#define GLOAD_LDS(gsrc, ldst) \
    __builtin_amdgcn_global_load_lds( \
        (const __attribute__((address_space(1))) void*)(gsrc), \
        (__attribute__((address_space(3))) void*)(ldst), 16, 0, 0)

// K0: build BbT[c][k] bf16, c<256 -> W heads, c>=256 -> Wr
__global__ __launch_bounds__(256) void k_wcvt(
    const float* __restrict__ w, const float* __restrict__ wr,
    unsigned short* __restrict__ BbT)
{
    int c = blockIdx.x;
    int k = threadIdx.x;
    float v;
    if (c < 256) {
        int head = c >> 6, f = c & 63;
        v = w[((size_t)head * IN_F + k) * HF + f];
    } else {
        v = wr[(size_t)k * OUT_F + (c - 256)];
    }
    BbT[(size_t)c * IN_F + k] = (unsigned short)f2bf(v);
}

// K1: MERGED gemm + pack. Blocks 0..511: fused GEMM [8192x256]@[256x512]
// -> hT | out residual. Blocks 512..8703: graph bit-pack (HBM-bound; the
// gemm blocks hide under its HBM stream).
__global__ __launch_bounds__(256) void k_gemm_pack(
    const float* __restrict__ x, const unsigned short* __restrict__ BbT,
    const float* __restrict__ bias,
    unsigned short* __restrict__ hT, float* __restrict__ out,
    const int* __restrict__ graph, unsigned int* __restrict__ bits)
{
    __shared__ unsigned short Asw[64 * 64];
    __shared__ unsigned short Bsw[128 * 64];
    int b = blockIdx.x;
    int t = threadIdx.x;

    if (b >= 512) {
        int p = b - 512;
        int jw = p & 255;
        int i = (p >> 8) * 256 + t;
        const int* gp = graph + (size_t)(jw * 32) * N + i;
        unsigned int word = 0;
        #pragma unroll
        for (int k = 0; k < 32; ++k)
            word |= (gp[(size_t)k * N] > 0 ? 1u : 0u) << k;
        bits[(size_t)jw * N + i] = word;
        return;
    }

    int m0 = (b & 127) * 64;
    int bn = b >> 7;
    int w_ = t >> 6, l = t & 63;
    int wr_ = w_ >> 1, wc_ = w_ & 1;
    int ar = l & 15, g = l >> 4;

    f32x4 acc[2][4];
    #pragma unroll
    for (int m = 0; m < 2; ++m)
        #pragma unroll
        for (int n = 0; n < 4; ++n) acc[m][n] = (f32x4){0.f, 0.f, 0.f, 0.f};

    int srow = t >> 2, skq = (t & 3) * 16;
    int sc = t >> 1, sh = (t & 1) * 32;

    for (int kt = 0; kt < 4; ++kt) {
        const float* xs = x + (size_t)(m0 + srow) * IN_F + kt * 64 + skq;
        float4 xa = ((const float4*)xs)[0];
        float4 xb = ((const float4*)xs)[1];
        float4 xc = ((const float4*)xs)[2];
        float4 xd = ((const float4*)xs)[3];
        unsigned ae[8];
        ae[0] = pack_bf16(xa.x, xa.y); ae[1] = pack_bf16(xa.z, xa.w);
        ae[2] = pack_bf16(xb.x, xb.y); ae[3] = pack_bf16(xb.z, xb.w);
        ae[4] = pack_bf16(xc.x, xc.y); ae[5] = pack_bf16(xc.z, xc.w);
        ae[6] = pack_bf16(xd.x, xd.y); ae[7] = pack_bf16(xd.z, xd.w);
        int kb0 = (skq >> 3) ^ (srow & 7);
        int kb1 = ((skq >> 3) + 1) ^ (srow & 7);
        *(uint4*)&Asw[srow * 64 + kb0 * 8] = *(uint4*)&ae[0];
        *(uint4*)&Asw[srow * 64 + kb1 * 8] = *(uint4*)&ae[4];
        const unsigned short* bs = BbT + (size_t)(bn * 128 + sc) * IN_F + kt * 64 + sh;
        uint4 b0 = ((const uint4*)bs)[0];
        uint4 b1 = ((const uint4*)bs)[1];
        uint4 b2 = ((const uint4*)bs)[2];
        uint4 b3 = ((const uint4*)bs)[3];
        int hb = sh >> 3;
        *(uint4*)&Bsw[sc * 64 + ((hb + 0) ^ (sc & 7)) * 8] = b0;
        *(uint4*)&Bsw[sc * 64 + ((hb + 1) ^ (sc & 7)) * 8] = b1;
        *(uint4*)&Bsw[sc * 64 + ((hb + 2) ^ (sc & 7)) * 8] = b2;
        *(uint4*)&Bsw[sc * 64 + ((hb + 3) ^ (sc & 7)) * 8] = b3;
        __syncthreads();
        #pragma unroll
        for (int ks = 0; ks < 2; ++ks) {
            short8 af[2], bf[4];
            #pragma unroll
            for (int m = 0; m < 2; ++m) {
                int row = wr_ * 32 + m * 16 + ar;
                int kb = (ks * 4 + g) ^ (row & 7);
                af[m] = *(const short8*)&Asw[row * 64 + kb * 8];
            }
            #pragma unroll
            for (int n = 0; n < 4; ++n) {
                int c = wc_ * 64 + n * 16 + ar;
                int kb = (ks * 4 + g) ^ (c & 7);
                bf[n] = *(const short8*)&Bsw[c * 64 + kb * 8];
            }
            #pragma unroll
            for (int m = 0; m < 2; ++m)
                #pragma unroll
                for (int n = 0; n < 4; ++n)
                    acc[m][n] = __builtin_amdgcn_mfma_f32_16x16x32_bf16(af[m], bf[n], acc[m][n], 0, 0, 0);
        }
        __syncthreads();
    }
    #pragma unroll
    for (int m = 0; m < 2; ++m) {
        #pragma unroll
        for (int n = 0; n < 4; ++n) {
            int cg = bn * 128 + wc_ * 64 + n * 16 + ar;
            int mg0 = m0 + wr_ * 32 + m * 16 + g * 4;
            if (cg < 256) {
                int head = cg >> 6, f = cg & 63;
                unsigned pk[2];
                pk[0] = pack_bf16(acc[m][n][0], acc[m][n][1]);
                pk[1] = pack_bf16(acc[m][n][2], acc[m][n][3]);
                *(uint2*)(hT + (size_t)(head * HF + f) * N + mg0) = *(uint2*)pk;
            } else {
                float bb = bias[cg - 256];
                #pragma unroll
                for (int r = 0; r < 4; ++r)
                    out[(size_t)(mg0 + r) * OUT_F + (cg - 256)] = acc[m][n][r] + bb;
            }
        }
    }
}

// K2: coe_i/coe_j from hT (column-major dot, coalesced)
__global__ __launch_bounds__(256) void k_coe(
    const unsigned short* __restrict__ hT, const float* __restrict__ wi,
    const float* __restrict__ wj, float* __restrict__ coe_i, float* __restrict__ coe_j)
{
    int head = blockIdx.y;
    int n = blockIdx.x * 256 + threadIdx.x;
    const unsigned short* hp = hT + (size_t)head * HF * N + n;
    float si = 0.f, sj = 0.f;
    #pragma unroll 8
    for (int f = 0; f < HF; ++f) {
        float hv = bf2f(hp[(size_t)f * N]);
        si = fmaf(hv, wi[head * HF + f], si);
        sj = fmaf(hv, wj[head * HF + f], sj);
    }
    coe_i[head * N + n] = si;
    coe_j[head * N + n] = sj;
}

// K3: per head: maxB + column factor arrays F=exp(b), H=exp(0.2b)
__global__ __launch_bounds__(256) void k_cols(
    const float* __restrict__ coe_j, float* __restrict__ maxB,
    float* __restrict__ F, float* __restrict__ H)
{
    __shared__ float red[256];
    int head = blockIdx.x;
    int t = threadIdx.x;
    float m = -1e30f;
    for (int n = t; n < N; n += 256) {
        float b = coe_j[head * N + n];
        F[head * N + n] = __expf(b);
        H[head * N + n] = __expf(0.2f * b);
        m = fmaxf(m, b);
    }
    red[t] = m;
    __syncthreads();
    for (int s = 128; s > 0; s >>= 1) {
        if (t < s) red[t] = fmaxf(red[t], red[t + s]);
        __syncthreads();
    }
    if (t == 0) maxB[head] = red[0];
}

// P for 8 columns: p = max(Ei*F, Gi*H) (= exp(lrelu(a+b)-M)); mask via sbfe.
__device__ __forceinline__ short8 makeP(
    const float4& fa, const float4& fb4, const float4& ha, const float4& hb4,
    unsigned int mk, float Ei, float Gi)
{
    float fv[8] = {fa.x, fa.y, fa.z, fa.w, fb4.x, fb4.y, fb4.z, fb4.w};
    float hv[8] = {ha.x, ha.y, ha.z, ha.w, hb4.x, hb4.y, hb4.z, hb4.w};
    union { short8 s8; unsigned u[4]; } A;
    #pragma unroll
    for (int jp = 0; jp < 4; ++jp) {
        float p0 = fmaxf(Ei * fv[2 * jp],     Gi * hv[2 * jp]);
        float p1 = fmaxf(Ei * fv[2 * jp + 1], Gi * hv[2 * jp + 1]);
        int s0 = __builtin_amdgcn_sbfe((int)mk, 2 * jp, 1);
        int s1 = __builtin_amdgcn_sbfe((int)mk, 2 * jp + 1, 1);
        p0 = __int_as_float(__float_as_int(p0) & s0);
        p1 = __int_as_float(__float_as_int(p1) & s1);
        A.u[jp] = pack_bf16(p0, p1);
    }
    return A.s8;
}

// K5: flash aggregate (round-7 structure), staging via global_load_lds:
// no ds_writes, no staging VGPRs; gloads issued right AFTER the barrier
// (prior readers of the target buffer provably done), drained by the NEXT
// barrier with a full iteration of cover. Swizzle preserved by pre-swizzled
// per-lane GLOBAL source (gg = slot^lrow) + linear per-wave LDS dest (m173).
// 8 waves = (rg:2 row-halves) x (grp:4 j-tiles), superstep = 256 j.
__global__ __launch_bounds__(512) void k_att(
    const unsigned short* __restrict__ hT, const float* __restrict__ coe_i,
    const float* __restrict__ maxB, const float* __restrict__ F,
    const float* __restrict__ H, const unsigned int* __restrict__ bits,
    float* __restrict__ out)
{
    __shared__ char smem[65536];
    unsigned short* hb = (unsigned short*)smem;   // [buf:2][tile:4][f:64][j:64 swizzled]
    float* mbuf = (float*)smem;                    // aliased merge buffer

    int t = threadIdx.x;
    int head = blockIdx.y;
    int i0 = blockIdx.x * 64;
    int w = t >> 6, l = t & 63;
    int rg = w >> 2, grp = w & 3;
    int ar = l & 15, g = l >> 4, g8 = g * 8;

    int irow0 = i0 + rg * 32 + ar;
    int irow1 = irow0 + 16;
    float mB = maxB[head];
    float a0 = coe_i[head * N + irow0];
    float a1 = coe_i[head * N + irow1];
    float M0 = lrelu(a0 + mB);
    float M1 = lrelu(a1 + mB);
    float Ei0 = __expf(a0 - M0), Gi0 = __expf(0.2f * a0 - M0);
    float Ei1 = __expf(a1 - M1), Gi1 = __expf(0.2f * a1 - M1);

    f32x4 acc0[4], acc1[4];
    #pragma unroll
    for (int fb = 0; fb < 4; ++fb) {
        acc0[fb] = (f32x4){0.f, 0.f, 0.f, 0.f};
        acc1[fb] = (f32x4){0.f, 0.f, 0.f, 0.f};
    }
    f32x4 accd0 = (f32x4){0.f, 0.f, 0.f, 0.f};
    f32x4 accd1 = (f32x4){0.f, 0.f, 0.f, 0.f};

    short8 ones;
    #pragma unroll
    for (int k = 0; k < 8; ++k) ones[k] = (short)0x3F80;

    // gload_lds staging geometry: wave w stages tile tg=w>>1, rows (w&1)*32 + q*8..+7.
    // lane l: row-in-group lrow=l>>3, granule slot=l&7; global granule gg = slot^lrow
    // (sf&7 == lrow), so LDS slot p holds global granule p^ (sf&7) — identical
    // mapping to the ds_read side's pg = (ss*4+g) ^ (ar&7).
    int tg = w >> 1;
    int rb0 = (w & 1) * 32;
    int lrow = l >> 3;
    int slot = l & 7;
    int gg = slot ^ lrow;
    const unsigned short* qsrc[4];
    #pragma unroll
    for (int q = 0; q < 4; ++q) {
        int sf = rb0 + q * 8 + lrow;
        qsrc[q] = hT + (size_t)(head * HF + sf) * N + tg * 64 + gg * 8;
    }
    int ldsoff0 = tg * 4096 + rb0 * 64;   // elems; wave-uniform; +q*512 per chunk

    const float* Fp = F + head * N + g8;
    const float* Hp = H + head * N + g8;
    const unsigned int* bp0 = bits + irow0;
    const unsigned int* bp1 = bits + irow1;

    // prolog: stage superstep 0 into buf 0
    #pragma unroll
    for (int q = 0; q < 4; ++q)
        GLOAD_LDS(qsrc[q], hb + ldsoff0 + q * 512);

    for (int s = 0; s < 32; ++s) {
        int jt = s * 256 + grp * 64;
        // mask gathers for this superstep (scattered L2)
        size_t jwd = (size_t)(jt >> 5);
        unsigned int mk00 = bp0[jwd * N] >> g8;
        unsigned int mk01 = bp0[(jwd + 1) * N] >> g8;
        unsigned int mk10 = bp1[jwd * N] >> g8;
        unsigned int mk11 = bp1[(jwd + 1) * N] >> g8;
        // F/H loads (L1-resident broadcasts) + A-fragments
        float4 fa0 = *(const float4*)(Fp + jt);
        float4 fb0 = *(const float4*)(Fp + jt + 4);
        float4 ha0 = *(const float4*)(Hp + jt);
        float4 hb0 = *(const float4*)(Hp + jt + 4);
        float4 fa1 = *(const float4*)(Fp + jt + 32);
        float4 fb1 = *(const float4*)(Fp + jt + 36);
        float4 ha1 = *(const float4*)(Hp + jt + 32);
        float4 hb1 = *(const float4*)(Hp + jt + 36);
        short8 af00 = makeP(fa0, fb0, ha0, hb0, mk00, Ei0, Gi0);
        short8 af10 = makeP(fa0, fb0, ha0, hb0, mk10, Ei1, Gi1);
        short8 af01 = makeP(fa1, fb1, ha1, hb1, mk01, Ei0, Gi0);
        short8 af11 = makeP(fa1, fb1, ha1, hb1, mk11, Ei1, Gi1);

        // barrier: buf[s&1]'s gloads (issued last iteration, full-iter cover)
        // drained here; prior readers of buf[(s+1)&1] done (lgkmcnt drain).
        __syncthreads();

        // issue next superstep's staging DMA into buf[(s+1)&1] — no registers,
        // no ds_write; completion enforced by NEXT iteration's barrier.
        if (s < 31) {
            int bon = ((s + 1) & 1) * 16384;
            int jn = (s + 1) * 256;
            #pragma unroll
            for (int q = 0; q < 4; ++q)
                GLOAD_LDS(qsrc[q] + jn, hb + bon + ldsoff0 + q * 512);
        }

        // MFMA block on buf[s&1]
        int bo = (s & 1) * 16384;
        const unsigned short* rbuf = &hb[bo + grp * 4096];
        #pragma unroll
        for (int ss = 0; ss < 2; ++ss) {
            short8 a0f = ss ? af01 : af00;
            short8 a1f = ss ? af11 : af10;
            #pragma unroll
            for (int fb = 0; fb < 4; ++fb) {
                int row = fb * 16 + ar;
                int pg = (ss * 4 + g) ^ (ar & 7);
                short8 bfr = *(const short8*)&rbuf[row * 64 + pg * 8];
                acc0[fb] = __builtin_amdgcn_mfma_f32_16x16x32_bf16(a0f, bfr, acc0[fb], 0, 0, 0);
                acc1[fb] = __builtin_amdgcn_mfma_f32_16x16x32_bf16(a1f, bfr, acc1[fb], 0, 0, 0);
            }
            accd0 = __builtin_amdgcn_mfma_f32_16x16x32_bf16(a0f, ones, accd0, 0, 0, 0);
            accd1 = __builtin_amdgcn_mfma_f32_16x16x32_bf16(a1f, ones, accd1, 0, 0, 0);
        }
    }

    // 4-way grp merge through aliased LDS
    __syncthreads();
    int slot_m = rg * 64 + l;
    if (grp > 0) {
        float* dst = mbuf + (size_t)(grp - 1) * 5248 + slot_m * 41;
        #pragma unroll
        for (int fb = 0; fb < 4; ++fb)
            #pragma unroll
            for (int r = 0; r < 4; ++r) {
                dst[fb * 4 + r] = acc0[fb][r];
                dst[16 + fb * 4 + r] = acc1[fb][r];
            }
        #pragma unroll
        for (int r = 0; r < 4; ++r) {
            dst[32 + r] = accd0[r];
            dst[36 + r] = accd1[r];
        }
    }
    __syncthreads();
    if (grp == 0) {
        #pragma unroll
        for (int q = 0; q < 3; ++q) {
            const float* src = mbuf + (size_t)q * 5248 + slot_m * 41;
            #pragma unroll
            for (int fb = 0; fb < 4; ++fb)
                #pragma unroll
                for (int r = 0; r < 4; ++r) {
                    acc0[fb][r] += src[fb * 4 + r];
                    acc1[fb][r] += src[16 + fb * 4 + r];
                }
            #pragma unroll
            for (int r = 0; r < 4; ++r) {
                accd0[r] += src[32 + r];
                accd1[r] += src[36 + r];
            }
        }
        #pragma unroll
        for (int r = 0; r < 4; ++r) {
            float inv0 = 1.0f / accd0[r];
            float inv1 = 1.0f / accd1[r];
            int orow0 = i0 + rg * 32 + g * 4 + r;
            float* op0 = out + (size_t)orow0 * OUT_F + head * HF + ar;
            float* op1 = op0 + 16 * OUT_F;
            #pragma unroll
            for (int fb = 0; fb < 4; ++fb) {
                op0[fb * 16] += acc0[fb][r] * inv0;
                op1[fb * 16] += acc1[fb][r] * inv1;
            }
        }
    }
}

extern "C" void kernel_launch(void* const* d_in, const int* in_sizes, int n_in,
                              void* d_out, int out_size, void* d_ws, size_t ws_size,
                              hipStream_t stream) {
    const float* x     = (const float*)d_in[0];
    const int*   graph = (const int*)d_in[1];
    const float* w     = (const float*)d_in[2];
    const float* wi    = (const float*)d_in[3];
    const float* wj    = (const float*)d_in[4];
    const float* wr    = (const float*)d_in[5];
    const float* bias  = (const float*)d_in[6];
    float* out = (float*)d_out;

    char* ws = (char*)d_ws;
    unsigned short* hT  = (unsigned short*)(ws);                    // 4,194,304
    float* coe_i = (float*)(ws + 4194304);                          // 131072
    float* coe_j = (float*)(ws + 4325376);                          // 131072
    float* maxB  = (float*)(ws + 4456448);                          // 1024
    float* F     = (float*)(ws + 4457472);                          // 131072
    float* H     = (float*)(ws + 4588544);                          // 131072
    unsigned short* BbT = (unsigned short*)(ws + 4719616);          // 262144
    unsigned int* bits  = (unsigned int*)(ws + 4981760);            // 8,388,608

    k_wcvt<<<dim3(512), 256, 0, stream>>>(w, wr, BbT);
    k_gemm_pack<<<dim3(512 + 8192), 256, 0, stream>>>(x, BbT, bias, hT, out, graph, bits);
    k_coe<<<dim3(32, 4), 256, 0, stream>>>(hT, wi, wj, coe_i, coe_j);
    k_cols<<<dim3(4), 256, 0, stream>>>(coe_j, maxB, F, H);
    k_att<<<dim3(N / 64, HEADS), 512, 0, stream>>>(hT, coe_i, maxB, F, H, bits, out);
}

// Round 14
// 157.888 us; speedup vs baseline: 1.4686x; 1.0388x over previous
//
#include <hip/hip_runtime.h>
#include <hip/hip_bf16.h>

#define N 8192
#define IN_F 256
#define HEADS 4
#define HF 64
#define OUT_F 256

typedef __attribute__((ext_vector_type(8))) short short8;
typedef __attribute__((ext_vector_type(4))) float f32x4;

__device__ __forceinline__ float lrelu(float x) {
    return fmaxf(x, 0.0f) * 0.8f + x * 0.2f;
}
__device__ __forceinline__ short f2bf(float f) {
    union { __hip_bfloat16 h; short s; } u;
    u.h = __float2bfloat16(f);
    return u.s;
}
__device__ __forceinline__ float bf2f(unsigned short b) {
    union { unsigned u; float f; } v; v.u = ((unsigned)b) << 16;
    return v.f;
}
__device__ __forceinline__ unsigned pack_bf16(float p0, float p1) {
    union { __hip_bfloat162 b; unsigned u; } cv;
    cv.b = __float22bfloat162_rn(make_float2(p0, p1));
    return cv.u;
}

// direct global->LDS DMA, 16B per lane; LDS dest is wave-uniform base + lane*16
#define GLOAD_LDS(gsrc, ldst) \
    __builtin_amdgcn_global_load_lds( \
        (const __attribute__((address_space(1))) void*)(gsrc), \
        (__attribute__((address_space(3))) void*)(ldst), 16, 0, 0)

// K0: build BbT[c][k] bf16, c<256 -> W heads, c>=256 -> Wr
__global__ __launch_bounds__(256) void k_wcvt(
    const float* __restrict__ w, const float* __restrict__ wr,
    unsigned short* __restrict__ BbT)
{
    int c = blockIdx.x;
    int k = threadIdx.x;
    float v;
    if (c < 256) {
        int head = c >> 6, f = c & 63;
        v = w[((size_t)head * IN_F + k) * HF + f];
    } else {
        v = wr[(size_t)k * OUT_F + (c - 256)];
    }
    BbT[(size_t)c * IN_F + k] = (unsigned short)f2bf(v);
}

// K1: MERGED gemm + pack + fused coe. Blocks 0..511: fused GEMM
// [8192x256]@[256x512] -> hT | out residual; blocks with bn<2 also reduce
// coe_i/coe_j straight from f32 accumulators (each wave owns exactly one
// head's 64 feature columns). Blocks 512..8703: graph bit-pack (HBM-bound;
// gemm blocks hide under its HBM stream).
__global__ __launch_bounds__(256) void k_gemm_pack(
    const float* __restrict__ x, const unsigned short* __restrict__ BbT,
    const float* __restrict__ bias, const float* __restrict__ wi,
    const float* __restrict__ wj,
    unsigned short* __restrict__ hT, float* __restrict__ out,
    float* __restrict__ coe_i, float* __restrict__ coe_j,
    const int* __restrict__ graph, unsigned int* __restrict__ bits)
{
    __shared__ unsigned short Asw[64 * 64];
    __shared__ unsigned short Bsw[128 * 64];
    int b = blockIdx.x;
    int t = threadIdx.x;

    if (b >= 512) {
        int p = b - 512;
        int jw = p & 255;
        int i = (p >> 8) * 256 + t;
        const int* gp = graph + (size_t)(jw * 32) * N + i;
        unsigned int word = 0;
        #pragma unroll
        for (int k = 0; k < 32; ++k)
            word |= (gp[(size_t)k * N] > 0 ? 1u : 0u) << k;
        bits[(size_t)jw * N + i] = word;
        return;
    }

    int m0 = (b & 127) * 64;
    int bn = b >> 7;
    int w_ = t >> 6, l = t & 63;
    int wr_ = w_ >> 1, wc_ = w_ & 1;
    int ar = l & 15, g = l >> 4;

    f32x4 acc[2][4];
    #pragma unroll
    for (int m = 0; m < 2; ++m)
        #pragma unroll
        for (int n = 0; n < 4; ++n) acc[m][n] = (f32x4){0.f, 0.f, 0.f, 0.f};

    int srow = t >> 2, skq = (t & 3) * 16;
    int sc = t >> 1, sh = (t & 1) * 32;

    for (int kt = 0; kt < 4; ++kt) {
        const float* xs = x + (size_t)(m0 + srow) * IN_F + kt * 64 + skq;
        float4 xa = ((const float4*)xs)[0];
        float4 xb = ((const float4*)xs)[1];
        float4 xc = ((const float4*)xs)[2];
        float4 xd = ((const float4*)xs)[3];
        unsigned ae[8];
        ae[0] = pack_bf16(xa.x, xa.y); ae[1] = pack_bf16(xa.z, xa.w);
        ae[2] = pack_bf16(xb.x, xb.y); ae[3] = pack_bf16(xb.z, xb.w);
        ae[4] = pack_bf16(xc.x, xc.y); ae[5] = pack_bf16(xc.z, xc.w);
        ae[6] = pack_bf16(xd.x, xd.y); ae[7] = pack_bf16(xd.z, xd.w);
        int kb0 = (skq >> 3) ^ (srow & 7);
        int kb1 = ((skq >> 3) + 1) ^ (srow & 7);
        *(uint4*)&Asw[srow * 64 + kb0 * 8] = *(uint4*)&ae[0];
        *(uint4*)&Asw[srow * 64 + kb1 * 8] = *(uint4*)&ae[4];
        const unsigned short* bs = BbT + (size_t)(bn * 128 + sc) * IN_F + kt * 64 + sh;
        uint4 b0 = ((const uint4*)bs)[0];
        uint4 b1 = ((const uint4*)bs)[1];
        uint4 b2 = ((const uint4*)bs)[2];
        uint4 b3 = ((const uint4*)bs)[3];
        int hb = sh >> 3;
        *(uint4*)&Bsw[sc * 64 + ((hb + 0) ^ (sc & 7)) * 8] = b0;
        *(uint4*)&Bsw[sc * 64 + ((hb + 1) ^ (sc & 7)) * 8] = b1;
        *(uint4*)&Bsw[sc * 64 + ((hb + 2) ^ (sc & 7)) * 8] = b2;
        *(uint4*)&Bsw[sc * 64 + ((hb + 3) ^ (sc & 7)) * 8] = b3;
        __syncthreads();
        #pragma unroll
        for (int ks = 0; ks < 2; ++ks) {
            short8 af[2], bf[4];
            #pragma unroll
            for (int m = 0; m < 2; ++m) {
                int row = wr_ * 32 + m * 16 + ar;
                int kb = (ks * 4 + g) ^ (row & 7);
                af[m] = *(const short8*)&Asw[row * 64 + kb * 8];
            }
            #pragma unroll
            for (int n = 0; n < 4; ++n) {
                int c = wc_ * 64 + n * 16 + ar;
                int kb = (ks * 4 + g) ^ (c & 7);
                bf[n] = *(const short8*)&Bsw[c * 64 + kb * 8];
            }
            #pragma unroll
            for (int m = 0; m < 2; ++m)
                #pragma unroll
                for (int n = 0; n < 4; ++n)
                    acc[m][n] = __builtin_amdgcn_mfma_f32_16x16x32_bf16(af[m], bf[n], acc[m][n], 0, 0, 0);
        }
        __syncthreads();
    }
    #pragma unroll
    for (int m = 0; m < 2; ++m) {
        #pragma unroll
        for (int n = 0; n < 4; ++n) {
            int cg = bn * 128 + wc_ * 64 + n * 16 + ar;
            int mg0 = m0 + wr_ * 32 + m * 16 + g * 4;
            if (cg < 256) {
                int head = cg >> 6, f = cg & 63;
                unsigned pk[2];
                pk[0] = pack_bf16(acc[m][n][0], acc[m][n][1]);
                pk[1] = pack_bf16(acc[m][n][2], acc[m][n][3]);
                *(uint2*)(hT + (size_t)(head * HF + f) * N + mg0) = *(uint2*)pk;
            } else {
                float bb = bias[cg - 256];
                #pragma unroll
                for (int r = 0; r < 4; ++r)
                    out[(size_t)(mg0 + r) * OUT_F + (cg - 256)] = acc[m][n][r] + bb;
            }
        }
    }
    // fused coe reduction: wave owns head = bn*2 + wc_ (only bn<2 blocks)
    if (bn < 2) {
        int head = bn * 2 + wc_;
        float pi[2][4], pj[2][4];
        #pragma unroll
        for (int m = 0; m < 2; ++m)
            #pragma unroll
            for (int r = 0; r < 4; ++r) { pi[m][r] = 0.f; pj[m][r] = 0.f; }
        #pragma unroll
        for (int n = 0; n < 4; ++n) {
            float wiv = wi[head * HF + n * 16 + ar];
            float wjv = wj[head * HF + n * 16 + ar];
            #pragma unroll
            for (int m = 0; m < 2; ++m)
                #pragma unroll
                for (int r = 0; r < 4; ++r) {
                    pi[m][r] = fmaf(acc[m][n][r], wiv, pi[m][r]);
                    pj[m][r] = fmaf(acc[m][n][r], wjv, pj[m][r]);
                }
        }
        #pragma unroll
        for (int o = 1; o <= 8; o <<= 1)
            #pragma unroll
            for (int m = 0; m < 2; ++m)
                #pragma unroll
                for (int r = 0; r < 4; ++r) {
                    pi[m][r] += __shfl_xor(pi[m][r], o, 64);
                    pj[m][r] += __shfl_xor(pj[m][r], o, 64);
                }
        if (ar == 0) {
            #pragma unroll
            for (int m = 0; m < 2; ++m)
                #pragma unroll
                for (int r = 0; r < 4; ++r) {
                    int row = m0 + wr_ * 32 + m * 16 + g * 4 + r;
                    coe_i[head * N + row] = pi[m][r];
                    coe_j[head * N + row] = pj[m][r];
                }
        }
    }
}

// K3: per head: maxB + column factor arrays F=exp(b), H=exp(0.2b)
__global__ __launch_bounds__(256) void k_cols(
    const float* __restrict__ coe_j, float* __restrict__ maxB,
    float* __restrict__ F, float* __restrict__ H)
{
    __shared__ float red[256];
    int head = blockIdx.x;
    int t = threadIdx.x;
    float m = -1e30f;
    for (int n = t; n < N; n += 256) {
        float b = coe_j[head * N + n];
        F[head * N + n] = __expf(b);
        H[head * N + n] = __expf(0.2f * b);
        m = fmaxf(m, b);
    }
    red[t] = m;
    __syncthreads();
    for (int s = 128; s > 0; s >>= 1) {
        if (t < s) red[t] = fmaxf(red[t], red[t + s]);
        __syncthreads();
    }
    if (t == 0) maxB[head] = red[0];
}

// P for 8 columns: p = max(Ei*F, Gi*H) (= exp(lrelu(a+b)-M)); mask via sbfe.
__device__ __forceinline__ short8 makeP(
    const float4& fa, const float4& fb4, const float4& ha, const float4& hb4,
    unsigned int mk, float Ei, float Gi)
{
    float fv[8] = {fa.x, fa.y, fa.z, fa.w, fb4.x, fb4.y, fb4.z, fb4.w};
    float hv[8] = {ha.x, ha.y, ha.z, ha.w, hb4.x, hb4.y, hb4.z, hb4.w};
    union { short8 s8; unsigned u[4]; } A;
    #pragma unroll
    for (int jp = 0; jp < 4; ++jp) {
        float p0 = fmaxf(Ei * fv[2 * jp],     Gi * hv[2 * jp]);
        float p1 = fmaxf(Ei * fv[2 * jp + 1], Gi * hv[2 * jp + 1]);
        int s0 = __builtin_amdgcn_sbfe((int)mk, 2 * jp, 1);
        int s1 = __builtin_amdgcn_sbfe((int)mk, 2 * jp + 1, 1);
        p0 = __int_as_float(__float_as_int(p0) & s0);
        p1 = __int_as_float(__float_as_int(p1) & s1);
        A.u[jp] = pack_bf16(p0, p1);
    }
    return A.s8;
}

// K5: flash aggregate (round-13 structure: global_load_lds staging).
// Round-14 change: mask gathers prefetched 1 superstep ahead, issued AFTER
// the barrier alongside the staging DMA — cover = MFMA block + next F/H;
// the barrier's vmcnt(0) drain never hits them mid-flight.
// 8 waves = (rg:2 row-halves) x (grp:4 j-tiles), superstep = 256 j.
__global__ __launch_bounds__(512) void k_att(
    const unsigned short* __restrict__ hT, const float* __restrict__ coe_i,
    const float* __restrict__ maxB, const float* __restrict__ F,
    const float* __restrict__ H, const unsigned int* __restrict__ bits,
    float* __restrict__ out)
{
    __shared__ char smem[65536];
    unsigned short* hb = (unsigned short*)smem;   // [buf:2][tile:4][f:64][j:64 swizzled]
    float* mbuf = (float*)smem;                    // aliased merge buffer

    int t = threadIdx.x;
    int head = blockIdx.y;
    int i0 = blockIdx.x * 64;
    int w = t >> 6, l = t & 63;
    int rg = w >> 2, grp = w & 3;
    int ar = l & 15, g = l >> 4, g8 = g * 8;

    int irow0 = i0 + rg * 32 + ar;
    int irow1 = irow0 + 16;
    float mB = maxB[head];
    float a0 = coe_i[head * N + irow0];
    float a1 = coe_i[head * N + irow1];
    float M0 = lrelu(a0 + mB);
    float M1 = lrelu(a1 + mB);
    float Ei0 = __expf(a0 - M0), Gi0 = __expf(0.2f * a0 - M0);
    float Ei1 = __expf(a1 - M1), Gi1 = __expf(0.2f * a1 - M1);

    f32x4 acc0[4], acc1[4];
    #pragma unroll
    for (int fb = 0; fb < 4; ++fb) {
        acc0[fb] = (f32x4){0.f, 0.f, 0.f, 0.f};
        acc1[fb] = (f32x4){0.f, 0.f, 0.f, 0.f};
    }
    f32x4 accd0 = (f32x4){0.f, 0.f, 0.f, 0.f};
    f32x4 accd1 = (f32x4){0.f, 0.f, 0.f, 0.f};

    short8 ones;
    #pragma unroll
    for (int k = 0; k < 8; ++k) ones[k] = (short)0x3F80;

    // gload_lds staging geometry (m173 pattern): wave w stages tile tg=w>>1,
    // rows (w&1)*32 + q*8..+7; lane l: lrow=l>>3, slot=l&7, global granule
    // gg = slot^lrow -> LDS slot p holds global granule p^(sf&7), identical
    // to the ds_read side's pg = (ss*4+g) ^ (ar&7).
    int tg = w >> 1;
    int rb0 = (w & 1) * 32;
    int lrow = l >> 3;
    int slot = l & 7;
    int gg = slot ^ lrow;
    const unsigned short* qsrc[4];
    #pragma unroll
    for (int q = 0; q < 4; ++q) {
        int sf = rb0 + q * 8 + lrow;
        qsrc[q] = hT + (size_t)(head * HF + sf) * N + tg * 64 + gg * 8;
    }
    int ldsoff0 = tg * 4096 + rb0 * 64;

    const float* Fp = F + head * N + g8;
    const float* Hp = H + head * N + g8;
    const unsigned int* bp0 = bits + irow0;
    const unsigned int* bp1 = bits + irow1;

    // prolog: stage superstep 0 into buf 0; masks for superstep 0
    #pragma unroll
    for (int q = 0; q < 4; ++q)
        GLOAD_LDS(qsrc[q], hb + ldsoff0 + q * 512);
    unsigned mk00, mk01, mk10, mk11;
    {
        int jt0 = grp * 64;
        size_t jw0 = (size_t)(jt0 >> 5);
        mk00 = bp0[jw0 * N] >> g8;
        mk01 = bp0[(jw0 + 1) * N] >> g8;
        mk10 = bp1[jw0 * N] >> g8;
        mk11 = bp1[(jw0 + 1) * N] >> g8;
    }

    for (int s = 0; s < 32; ++s) {
        int jt = s * 256 + grp * 64;
        // F/H loads (L1-resident broadcasts) + A-fragments from prefetched masks
        float4 fa0 = *(const float4*)(Fp + jt);
        float4 fb0 = *(const float4*)(Fp + jt + 4);
        float4 ha0 = *(const float4*)(Hp + jt);
        float4 hb0 = *(const float4*)(Hp + jt + 4);
        float4 fa1 = *(const float4*)(Fp + jt + 32);
        float4 fb1 = *(const float4*)(Fp + jt + 36);
        float4 ha1 = *(const float4*)(Hp + jt + 32);
        float4 hb1 = *(const float4*)(Hp + jt + 36);
        short8 af00 = makeP(fa0, fb0, ha0, hb0, mk00, Ei0, Gi0);
        short8 af10 = makeP(fa0, fb0, ha0, hb0, mk10, Ei1, Gi1);
        short8 af01 = makeP(fa1, fb1, ha1, hb1, mk01, Ei0, Gi0);
        short8 af11 = makeP(fa1, fb1, ha1, hb1, mk11, Ei1, Gi1);

        // barrier: buf[s&1]'s gloads (issued last iteration) drained here;
        // prior readers of buf[(s+1)&1] done.
        __syncthreads();

        // issue next superstep's staging DMA + mask gathers (both covered by
        // the MFMA block below + next iteration's pre-barrier phase)
        if (s < 31) {
            int bon = ((s + 1) & 1) * 16384;
            int jn = (s + 1) * 256;
            #pragma unroll
            for (int q = 0; q < 4; ++q)
                GLOAD_LDS(qsrc[q] + jn, hb + bon + ldsoff0 + q * 512);
        }
        int sn = (s + 1 < 32) ? s + 1 : s;
        size_t jwn = (size_t)(((size_t)sn * 256 + grp * 64) >> 5);
        unsigned nk00 = bp0[jwn * N] >> g8;
        unsigned nk01 = bp0[(jwn + 1) * N] >> g8;
        unsigned nk10 = bp1[jwn * N] >> g8;
        unsigned nk11 = bp1[(jwn + 1) * N] >> g8;

        // MFMA block on buf[s&1]
        int bo = (s & 1) * 16384;
        const unsigned short* rbuf = &hb[bo + grp * 4096];
        #pragma unroll
        for (int ss = 0; ss < 2; ++ss) {
            short8 a0f = ss ? af01 : af00;
            short8 a1f = ss ? af11 : af10;
            #pragma unroll
            for (int fb = 0; fb < 4; ++fb) {
                int row = fb * 16 + ar;
                int pg = (ss * 4 + g) ^ (ar & 7);
                short8 bfr = *(const short8*)&rbuf[row * 64 + pg * 8];
                acc0[fb] = __builtin_amdgcn_mfma_f32_16x16x32_bf16(a0f, bfr, acc0[fb], 0, 0, 0);
                acc1[fb] = __builtin_amdgcn_mfma_f32_16x16x32_bf16(a1f, bfr, acc1[fb], 0, 0, 0);
            }
            accd0 = __builtin_amdgcn_mfma_f32_16x16x32_bf16(a0f, ones, accd0, 0, 0, 0);
            accd1 = __builtin_amdgcn_mfma_f32_16x16x32_bf16(a1f, ones, accd1, 0, 0, 0);
        }
        mk00 = nk00; mk01 = nk01; mk10 = nk10; mk11 = nk11;
    }

    // 4-way grp merge through aliased LDS
    __syncthreads();
    int slot_m = rg * 64 + l;
    if (grp > 0) {
        float* dst = mbuf + (size_t)(grp - 1) * 5248 + slot_m * 41;
        #pragma unroll
        for (int fb = 0; fb < 4; ++fb)
            #pragma unroll
            for (int r = 0; r < 4; ++r) {
                dst[fb * 4 + r] = acc0[fb][r];
                dst[16 + fb * 4 + r] = acc1[fb][r];
            }
        #pragma unroll
        for (int r = 0; r < 4; ++r) {
            dst[32 + r] = accd0[r];
            dst[36 + r] = accd1[r];
        }
    }
    __syncthreads();
    if (grp == 0) {
        #pragma unroll
        for (int q = 0; q < 3; ++q) {
            const float* src = mbuf + (size_t)q * 5248 + slot_m * 41;
            #pragma unroll
            for (int fb = 0; fb < 4; ++fb)
                #pragma unroll
                for (int r = 0; r < 4; ++r) {
                    acc0[fb][r] += src[fb * 4 + r];
                    acc1[fb][r] += src[16 + fb * 4 + r];
                }
            #pragma unroll
            for (int r = 0; r < 4; ++r) {
                accd0[r] += src[32 + r];
                accd1[r] += src[36 + r];
            }
        }
        #pragma unroll
        for (int r = 0; r < 4; ++r) {
            float inv0 = 1.0f / accd0[r];
            float inv1 = 1.0f / accd1[r];
            int orow0 = i0 + rg * 32 + g * 4 + r;
            float* op0 = out + (size_t)orow0 * OUT_F + head * HF + ar;
            float* op1 = op0 + 16 * OUT_F;
            #pragma unroll
            for (int fb = 0; fb < 4; ++fb) {
                op0[fb * 16] += acc0[fb][r] * inv0;
                op1[fb * 16] += acc1[fb][r] * inv1;
            }
        }
    }
}

extern "C" void kernel_launch(void* const* d_in, const int* in_sizes, int n_in,
                              void* d_out, int out_size, void* d_ws, size_t ws_size,
                              hipStream_t stream) {
    const float* x     = (const float*)d_in[0];
    const int*   graph = (const int*)d_in[1];
    const float* w     = (const float*)d_in[2];
    const float* wi    = (const float*)d_in[3];
    const float* wj    = (const float*)d_in[4];
    const float* wr    = (const float*)d_in[5];
    const float* bias  = (const float*)d_in[6];
    float* out = (float*)d_out;

    char* ws = (char*)d_ws;
    unsigned short* hT  = (unsigned short*)(ws);                    // 4,194,304
    float* coe_i = (float*)(ws + 4194304);                          // 131072
    float* coe_j = (float*)(ws + 4325376);                          // 131072
    float* maxB  = (float*)(ws + 4456448);                          // 1024
    float* F     = (float*)(ws + 4457472);                          // 131072
    float* H     = (float*)(ws + 4588544);                          // 131072
    unsigned short* BbT = (unsigned short*)(ws + 4719616);          // 262144
    unsigned int* bits  = (unsigned int*)(ws + 4981760);            // 8,388,608

    k_wcvt<<<dim3(512), 256, 0, stream>>>(w, wr, BbT);
    k_gemm_pack<<<dim3(512 + 8192), 256, 0, stream>>>(x, BbT, bias, wi, wj, hT, out, coe_i, coe_j, graph, bits);
    k_cols<<<dim3(4), 256, 0, stream>>>(coe_j, maxB, F, H);
    k_att<<<dim3(N / 64, HEADS), 512, 0, stream>>>(hT, coe_i, maxB, F, H, bits, out);
}

// Round 15
// 156.446 us; speedup vs baseline: 1.4821x; 1.0092x over previous
//
#include <hip/hip_runtime.h>
#include <hip/hip_bf16.h>

#define N 8192
#define IN_F 256
#define HEADS 4
#define HF 64
#define OUT_F 256

typedef __attribute__((ext_vector_type(8))) short short8;
typedef __attribute__((ext_vector_type(4))) float f32x4;

__device__ __forceinline__ float lrelu(float x) {
    return fmaxf(x, 0.0f) * 0.8f + x * 0.2f;
}
__device__ __forceinline__ short f2bf(float f) {
    union { __hip_bfloat16 h; short s; } u;
    u.h = __float2bfloat16(f);
    return u.s;
}
__device__ __forceinline__ float bf2f(unsigned short b) {
    union { unsigned u; float f; } v; v.u = ((unsigned)b) << 16;
    return v.f;
}
__device__ __forceinline__ unsigned pack_bf16(float p0, float p1) {
    union { __hip_bfloat162 b; unsigned u; } cv;
    cv.b = __float22bfloat162_rn(make_float2(p0, p1));
    return cv.u;
}

// direct global->LDS DMA, 16B per lane; LDS dest is wave-uniform base + lane*16
#define GLOAD_LDS(gsrc, ldst) \
    __builtin_amdgcn_global_load_lds( \
        (const __attribute__((address_space(1))) void*)(gsrc), \
        (__attribute__((address_space(3))) void*)(ldst), 16, 0, 0)

#define MFMA16 __builtin_amdgcn_mfma_f32_16x16x32_bf16

// K0: build BbT[c][k] bf16, c<256 -> W heads, c>=256 -> Wr
__global__ __launch_bounds__(256) void k_wcvt(
    const float* __restrict__ w, const float* __restrict__ wr,
    unsigned short* __restrict__ BbT)
{
    int c = blockIdx.x;
    int k = threadIdx.x;
    float v;
    if (c < 256) {
        int head = c >> 6, f = c & 63;
        v = w[((size_t)head * IN_F + k) * HF + f];
    } else {
        v = wr[(size_t)k * OUT_F + (c - 256)];
    }
    BbT[(size_t)c * IN_F + k] = (unsigned short)f2bf(v);
}

// K1: MERGED gemm + pack + fused coe (validated r14 version, unchanged).
__global__ __launch_bounds__(256) void k_gemm_pack(
    const float* __restrict__ x, const unsigned short* __restrict__ BbT,
    const float* __restrict__ bias, const float* __restrict__ wi,
    const float* __restrict__ wj,
    unsigned short* __restrict__ hT, float* __restrict__ out,
    float* __restrict__ coe_i, float* __restrict__ coe_j,
    const int* __restrict__ graph, unsigned int* __restrict__ bits)
{
    __shared__ unsigned short Asw[64 * 64];
    __shared__ unsigned short Bsw[128 * 64];
    int b = blockIdx.x;
    int t = threadIdx.x;

    if (b >= 512) {
        int p = b - 512;
        int jw = p & 255;
        int i = (p >> 8) * 256 + t;
        const int* gp = graph + (size_t)(jw * 32) * N + i;
        unsigned int word = 0;
        #pragma unroll
        for (int k = 0; k < 32; ++k)
            word |= (gp[(size_t)k * N] > 0 ? 1u : 0u) << k;
        bits[(size_t)jw * N + i] = word;
        return;
    }

    int m0 = (b & 127) * 64;
    int bn = b >> 7;
    int w_ = t >> 6, l = t & 63;
    int wr_ = w_ >> 1, wc_ = w_ & 1;
    int ar = l & 15, g = l >> 4;

    f32x4 acc[2][4];
    #pragma unroll
    for (int m = 0; m < 2; ++m)
        #pragma unroll
        for (int n = 0; n < 4; ++n) acc[m][n] = (f32x4){0.f, 0.f, 0.f, 0.f};

    int srow = t >> 2, skq = (t & 3) * 16;
    int sc = t >> 1, sh = (t & 1) * 32;

    for (int kt = 0; kt < 4; ++kt) {
        const float* xs = x + (size_t)(m0 + srow) * IN_F + kt * 64 + skq;
        float4 xa = ((const float4*)xs)[0];
        float4 xb = ((const float4*)xs)[1];
        float4 xc = ((const float4*)xs)[2];
        float4 xd = ((const float4*)xs)[3];
        unsigned ae[8];
        ae[0] = pack_bf16(xa.x, xa.y); ae[1] = pack_bf16(xa.z, xa.w);
        ae[2] = pack_bf16(xb.x, xb.y); ae[3] = pack_bf16(xb.z, xb.w);
        ae[4] = pack_bf16(xc.x, xc.y); ae[5] = pack_bf16(xc.z, xc.w);
        ae[6] = pack_bf16(xd.x, xd.y); ae[7] = pack_bf16(xd.z, xd.w);
        int kb0 = (skq >> 3) ^ (srow & 7);
        int kb1 = ((skq >> 3) + 1) ^ (srow & 7);
        *(uint4*)&Asw[srow * 64 + kb0 * 8] = *(uint4*)&ae[0];
        *(uint4*)&Asw[srow * 64 + kb1 * 8] = *(uint4*)&ae[4];
        const unsigned short* bs = BbT + (size_t)(bn * 128 + sc) * IN_F + kt * 64 + sh;
        uint4 b0 = ((const uint4*)bs)[0];
        uint4 b1 = ((const uint4*)bs)[1];
        uint4 b2 = ((const uint4*)bs)[2];
        uint4 b3 = ((const uint4*)bs)[3];
        int hb = sh >> 3;
        *(uint4*)&Bsw[sc * 64 + ((hb + 0) ^ (sc & 7)) * 8] = b0;
        *(uint4*)&Bsw[sc * 64 + ((hb + 1) ^ (sc & 7)) * 8] = b1;
        *(uint4*)&Bsw[sc * 64 + ((hb + 2) ^ (sc & 7)) * 8] = b2;
        *(uint4*)&Bsw[sc * 64 + ((hb + 3) ^ (sc & 7)) * 8] = b3;
        __syncthreads();
        #pragma unroll
        for (int ks = 0; ks < 2; ++ks) {
            short8 af[2], bf[4];
            #pragma unroll
            for (int m = 0; m < 2; ++m) {
                int row = wr_ * 32 + m * 16 + ar;
                int kb = (ks * 4 + g) ^ (row & 7);
                af[m] = *(const short8*)&Asw[row * 64 + kb * 8];
            }
            #pragma unroll
            for (int n = 0; n < 4; ++n) {
                int c = wc_ * 64 + n * 16 + ar;
                int kb = (ks * 4 + g) ^ (c & 7);
                bf[n] = *(const short8*)&Bsw[c * 64 + kb * 8];
            }
            #pragma unroll
            for (int m = 0; m < 2; ++m)
                #pragma unroll
                for (int n = 0; n < 4; ++n)
                    acc[m][n] = MFMA16(af[m], bf[n], acc[m][n], 0, 0, 0);
        }
        __syncthreads();
    }
    #pragma unroll
    for (int m = 0; m < 2; ++m) {
        #pragma unroll
        for (int n = 0; n < 4; ++n) {
            int cg = bn * 128 + wc_ * 64 + n * 16 + ar;
            int mg0 = m0 + wr_ * 32 + m * 16 + g * 4;
            if (cg < 256) {
                int head = cg >> 6, f = cg & 63;
                unsigned pk[2];
                pk[0] = pack_bf16(acc[m][n][0], acc[m][n][1]);
                pk[1] = pack_bf16(acc[m][n][2], acc[m][n][3]);
                *(uint2*)(hT + (size_t)(head * HF + f) * N + mg0) = *(uint2*)pk;
            } else {
                float bb = bias[cg - 256];
                #pragma unroll
                for (int r = 0; r < 4; ++r)
                    out[(size_t)(mg0 + r) * OUT_F + (cg - 256)] = acc[m][n][r] + bb;
            }
        }
    }
    if (bn < 2) {
        int head = bn * 2 + wc_;
        float pi[2][4], pj[2][4];
        #pragma unroll
        for (int m = 0; m < 2; ++m)
            #pragma unroll
            for (int r = 0; r < 4; ++r) { pi[m][r] = 0.f; pj[m][r] = 0.f; }
        #pragma unroll
        for (int n = 0; n < 4; ++n) {
            float wiv = wi[head * HF + n * 16 + ar];
            float wjv = wj[head * HF + n * 16 + ar];
            #pragma unroll
            for (int m = 0; m < 2; ++m)
                #pragma unroll
                for (int r = 0; r < 4; ++r) {
                    pi[m][r] = fmaf(acc[m][n][r], wiv, pi[m][r]);
                    pj[m][r] = fmaf(acc[m][n][r], wjv, pj[m][r]);
                }
        }
        #pragma unroll
        for (int o = 1; o <= 8; o <<= 1)
            #pragma unroll
            for (int m = 0; m < 2; ++m)
                #pragma unroll
                for (int r = 0; r < 4; ++r) {
                    pi[m][r] += __shfl_xor(pi[m][r], o, 64);
                    pj[m][r] += __shfl_xor(pj[m][r], o, 64);
                }
        if (ar == 0) {
            #pragma unroll
            for (int m = 0; m < 2; ++m)
                #pragma unroll
                for (int r = 0; r < 4; ++r) {
                    int row = m0 + wr_ * 32 + m * 16 + g * 4 + r;
                    coe_i[head * N + row] = pi[m][r];
                    coe_j[head * N + row] = pj[m][r];
                }
        }
    }
}

// K3: per head: maxB + column factor arrays F=exp(b), H=exp(0.2b)
__global__ __launch_bounds__(256) void k_cols(
    const float* __restrict__ coe_j, float* __restrict__ maxB,
    float* __restrict__ F, float* __restrict__ H)
{
    __shared__ float red[256];
    int head = blockIdx.x;
    int t = threadIdx.x;
    float m = -1e30f;
    for (int n = t; n < N; n += 256) {
        float b = coe_j[head * N + n];
        F[head * N + n] = __expf(b);
        H[head * N + n] = __expf(0.2f * b);
        m = fmaxf(m, b);
    }
    red[t] = m;
    __syncthreads();
    for (int s = 128; s > 0; s >>= 1) {
        if (t < s) red[t] = fmaxf(red[t], red[t + s]);
        __syncthreads();
    }
    if (t == 0) maxB[head] = red[0];
}

// P for 8 columns: p = max(Ei*F, Gi*H) (= exp(lrelu(a+b)-M)); mask via sbfe.
__device__ __forceinline__ short8 makeP(
    const float4& fa, const float4& fb4, const float4& ha, const float4& hb4,
    unsigned int mk, float Ei, float Gi)
{
    float fv[8] = {fa.x, fa.y, fa.z, fa.w, fb4.x, fb4.y, fb4.z, fb4.w};
    float hv[8] = {ha.x, ha.y, ha.z, ha.w, hb4.x, hb4.y, hb4.z, hb4.w};
    union { short8 s8; unsigned u[4]; } A;
    #pragma unroll
    for (int jp = 0; jp < 4; ++jp) {
        float p0 = fmaxf(Ei * fv[2 * jp],     Gi * hv[2 * jp]);
        float p1 = fmaxf(Ei * fv[2 * jp + 1], Gi * hv[2 * jp + 1]);
        int s0 = __builtin_amdgcn_sbfe((int)mk, 2 * jp, 1);
        int s1 = __builtin_amdgcn_sbfe((int)mk, 2 * jp + 1, 1);
        p0 = __int_as_float(__float_as_int(p0) & s0);
        p1 = __int_as_float(__float_as_int(p1) & s1);
        A.u[jp] = pack_bf16(p0, p1);
    }
    return A.s8;
}

__device__ __forceinline__ void merge_write(float* dst, f32x4 (&acc)[4][4], f32x4 (&accd)[4]) {
    #pragma unroll
    for (int rg = 0; rg < 4; ++rg) {
        #pragma unroll
        for (int fb = 0; fb < 4; ++fb)
            #pragma unroll
            for (int r = 0; r < 4; ++r)
                dst[rg * 16 + fb * 4 + r] = acc[rg][fb][r];
        #pragma unroll
        for (int r = 0; r < 4; ++r)
            dst[64 + rg * 4 + r] = accd[rg][r];
    }
}
__device__ __forceinline__ void merge_add(const float* src, f32x4 (&acc)[4][4], f32x4 (&accd)[4]) {
    #pragma unroll
    for (int rg = 0; rg < 4; ++rg) {
        #pragma unroll
        for (int fb = 0; fb < 4; ++fb)
            #pragma unroll
            for (int r = 0; r < 4; ++r)
                acc[rg][fb][r] += src[rg * 16 + fb * 4 + r];
        #pragma unroll
        for (int r = 0; r < 4; ++r)
            accd[rg][r] += src[64 + rg * 4 + r];
    }
}

// K5: flash aggregate, PER-WAVE BARRIER-FREE pipeline. Each wave: M=64 output
// rows x private 1024-j range, private 64f x 32j double-buffered LDS tile
// (8KB/wave, 64KB total). Per iter: issue 12 VMEM prefetches for s+1
// (4 gload_lds + 4 masks + 4 F/H), then s_waitcnt vmcnt(12) — FIFO retire
// means everything older (incl. gload(s)) is complete. No __syncthreads in
// the main loop; 8-way merge via LDS at the end. Each ds_read B-frag feeds
// 4 row-group MFMAs (2x reuse vs r14).
__global__ __launch_bounds__(512) void k_att(
    const unsigned short* __restrict__ hT, const float* __restrict__ coe_i,
    const float* __restrict__ maxB, const float* __restrict__ F,
    const float* __restrict__ H, const unsigned int* __restrict__ bits,
    float* __restrict__ out)
{
    __shared__ char smem[65536];

    int t = threadIdx.x;
    int head = blockIdx.y;
    int i0 = blockIdx.x * 64;
    int w = t >> 6, l = t & 63;
    int ar = l & 15, g = l >> 4, g8 = g * 8;

    float mB = maxB[head];
    float Eiv[4], Giv[4];
    #pragma unroll
    for (int rg = 0; rg < 4; ++rg) {
        float a = coe_i[head * N + i0 + rg * 16 + ar];
        float M = lrelu(a + mB);
        Eiv[rg] = __expf(a - M);
        Giv[rg] = __expf(0.2f * a - M);
    }

    f32x4 acc[4][4];
    f32x4 accd[4];
    #pragma unroll
    for (int rg = 0; rg < 4; ++rg) {
        #pragma unroll
        for (int fb = 0; fb < 4; ++fb) acc[rg][fb] = (f32x4){0.f, 0.f, 0.f, 0.f};
        accd[rg] = (f32x4){0.f, 0.f, 0.f, 0.f};
    }

    short8 ones;
    #pragma unroll
    for (int k = 0; k < 8; ++k) ones[k] = (short)0x3F80;

    // private LDS tile: [buf:2][64f][32j], 4KB per buf; swizzle: LDS granule
    // slot p at row f holds global granule p ^ (f&3).
    unsigned short* lbase = (unsigned short*)(smem + w * 8192);
    // gload q stages rows q*16 + (l>>2), granule slot l&3 (1KB per gload)
    int srq = l >> 2;
    int sslot = l & 3;
    const unsigned short* qsrc[4];
    #pragma unroll
    for (int q = 0; q < 4; ++q) {
        int row = q * 16 + srq;
        int gg = sslot ^ (row & 3);
        qsrc[q] = hT + (size_t)(head * HF + row) * N + gg * 8;
    }

    const float* Fp = F + head * N + g8;
    const float* Hp = H + head * N + g8;
    const unsigned int* bbase = bits + i0 + ar;

    int j0 = w * 1024;   // private j-range [j0, j0+1024)

    // prolog: stage tile 0 into buf 0; load masks + F/H for tile 0
    #pragma unroll
    for (int q = 0; q < 4; ++q)
        GLOAD_LDS(qsrc[q] + j0, lbase + q * 512);
    unsigned mk0, mk1, mk2, mk3;
    float4 cfa, cfb, cha, chb;
    {
        size_t jw0 = (size_t)(j0 >> 5);
        mk0 = bbase[jw0 * N +  0] >> g8;
        mk1 = bbase[jw0 * N + 16] >> g8;
        mk2 = bbase[jw0 * N + 32] >> g8;
        mk3 = bbase[jw0 * N + 48] >> g8;
        cfa = *(const float4*)(Fp + j0);
        cfb = *(const float4*)(Fp + j0 + 4);
        cha = *(const float4*)(Hp + j0);
        chb = *(const float4*)(Hp + j0 + 4);
    }

    #pragma unroll 1
    for (int s = 0; s < 32; ++s) {
        int jt = j0 + s * 32;
        int sn = (s + 1 < 32) ? s + 1 : 0;     // last iter wraps (discarded)
        int jtn = j0 + sn * 32;
        // issue next tile's 12 VMEM prefetches
        #pragma unroll
        for (int q = 0; q < 4; ++q)
            GLOAD_LDS(qsrc[q] + jtn, lbase + ((s + 1) & 1) * 2048 + q * 512);
        size_t jwn = (size_t)(jtn >> 5);
        unsigned nk0 = bbase[jwn * N +  0] >> g8;
        unsigned nk1 = bbase[jwn * N + 16] >> g8;
        unsigned nk2 = bbase[jwn * N + 32] >> g8;
        unsigned nk3 = bbase[jwn * N + 48] >> g8;
        float4 nfa = *(const float4*)(Fp + jtn);
        float4 nfb = *(const float4*)(Fp + jtn + 4);
        float4 nha = *(const float4*)(Hp + jtn);
        float4 nhb = *(const float4*)(Hp + jtn + 4);

        // wait: <=12 outstanding VMEM -> everything older (gload(s), mask(s),
        // F/H(s)) retired. No barrier; wave-local only.
        asm volatile("s_waitcnt vmcnt(12)" ::: "memory");
        __builtin_amdgcn_sched_barrier(0);

        // A-fragments from current (prefetched) inputs
        short8 af0 = makeP(cfa, cfb, cha, chb, mk0, Eiv[0], Giv[0]);
        short8 af1 = makeP(cfa, cfb, cha, chb, mk1, Eiv[1], Giv[1]);
        short8 af2 = makeP(cfa, cfb, cha, chb, mk2, Eiv[2], Giv[2]);
        short8 af3 = makeP(cfa, cfb, cha, chb, mk3, Eiv[3], Giv[3]);

        // ds_read B-frags from buf[s&1]; each feeds 4 row-group MFMAs
        const unsigned short* rbuf = lbase + (s & 1) * 2048;
        #pragma unroll
        for (int fb = 0; fb < 4; ++fb) {
            int row = fb * 16 + ar;
            int pg = g ^ (ar & 3);
            short8 bfr = *(const short8*)&rbuf[row * 32 + pg * 8];
            acc[0][fb] = MFMA16(af0, bfr, acc[0][fb], 0, 0, 0);
            acc[1][fb] = MFMA16(af1, bfr, acc[1][fb], 0, 0, 0);
            acc[2][fb] = MFMA16(af2, bfr, acc[2][fb], 0, 0, 0);
            acc[3][fb] = MFMA16(af3, bfr, acc[3][fb], 0, 0, 0);
        }
        accd[0] = MFMA16(af0, ones, accd[0], 0, 0, 0);
        accd[1] = MFMA16(af1, ones, accd[1], 0, 0, 0);
        accd[2] = MFMA16(af2, ones, accd[2], 0, 0, 0);
        accd[3] = MFMA16(af3, ones, accd[3], 0, 0, 0);

        // rotate prefetched inputs
        mk0 = nk0; mk1 = nk1; mk2 = nk2; mk3 = nk3;
        cfa = nfa; cfb = nfb; cha = nha; chb = nhb;
    }

    // ---- 8-way merge via LDS (pairwise, 2 writers per sub-round: 41.5KB) ----
    __syncthreads();   // all waves done with private tiles
    float* fm = (float*)smem;
    int ls = l * 81;
    // R1a: w0+=w4, w1+=w5
    if (w == 4 || w == 5) merge_write(fm + ((w - 4) * 64 * 81) + ls, acc, accd);
    __syncthreads();
    if (w < 2) merge_add(fm + (w * 64 * 81) + ls, acc, accd);
    __syncthreads();
    // R1b: w2+=w6, w3+=w7
    if (w == 6 || w == 7) merge_write(fm + ((w - 6) * 64 * 81) + ls, acc, accd);
    __syncthreads();
    if (w == 2 || w == 3) merge_add(fm + ((w - 2) * 64 * 81) + ls, acc, accd);
    __syncthreads();
    // R2: w0+=w2, w1+=w3
    if (w == 2 || w == 3) merge_write(fm + ((w - 2) * 64 * 81) + ls, acc, accd);
    __syncthreads();
    if (w < 2) merge_add(fm + (w * 64 * 81) + ls, acc, accd);
    __syncthreads();
    // R3: w0+=w1
    if (w == 1) merge_write(fm + ls, acc, accd);
    __syncthreads();
    if (w == 0) {
        merge_add(fm + ls, acc, accd);
        #pragma unroll
        for (int rg = 0; rg < 4; ++rg) {
            #pragma unroll
            for (int r = 0; r < 4; ++r) {
                float inv = 1.0f / accd[rg][r];
                int orow = i0 + rg * 16 + g * 4 + r;
                float* op = out + (size_t)orow * OUT_F + head * HF + ar;
                #pragma unroll
                for (int fb = 0; fb < 4; ++fb)
                    op[fb * 16] += acc[rg][fb][r] * inv;
            }
        }
    }
}

extern "C" void kernel_launch(void* const* d_in, const int* in_sizes, int n_in,
                              void* d_out, int out_size, void* d_ws, size_t ws_size,
                              hipStream_t stream) {
    const float* x     = (const float*)d_in[0];
    const int*   graph = (const int*)d_in[1];
    const float* w     = (const float*)d_in[2];
    const float* wi    = (const float*)d_in[3];
    const float* wj    = (const float*)d_in[4];
    const float* wr    = (const float*)d_in[5];
    const float* bias  = (const float*)d_in[6];
    float* out = (float*)d_out;

    char* ws = (char*)d_ws;
    unsigned short* hT  = (unsigned short*)(ws);                    // 4,194,304
    float* coe_i = (float*)(ws + 4194304);                          // 131072
    float* coe_j = (float*)(ws + 4325376);                          // 131072
    float* maxB  = (float*)(ws + 4456448);                          // 1024
    float* F     = (float*)(ws + 4457472);                          // 131072
    float* H     = (float*)(ws + 4588544);                          // 131072
    unsigned short* BbT = (unsigned short*)(ws + 4719616);          // 262144
    unsigned int* bits  = (unsigned int*)(ws + 4981760);            // 8,388,608

    k_wcvt<<<dim3(512), 256, 0, stream>>>(w, wr, BbT);
    k_gemm_pack<<<dim3(512 + 8192), 256, 0, stream>>>(x, BbT, bias, wi, wj, hT, out, coe_i, coe_j, graph, bits);
    k_cols<<<dim3(4), 256, 0, stream>>>(coe_j, maxB, F, H);
    k_att<<<dim3(N / 64, HEADS), 512, 0, stream>>>(hT, coe_i, maxB, F, H, bits, out);
}